// Round 15
// baseline (213.603 us; speedup 1.0000x reference)
//
#include <hip/hip_runtime.h>

#define NB 32
#define NI 2048
#define NP 16
#define NJ 32
#define ND 32
#define EPSF 1e-7f

typedef __attribute__((ext_vector_type(8))) short bf16x8;
typedef __attribute__((ext_vector_type(16))) float f32x16;
typedef __attribute__((ext_vector_type(4))) float f32x4;

static __device__ __forceinline__ unsigned cvt_pk_bf16(float lo, float hi) {
  unsigned r;
  asm("v_cvt_pk_bf16_f32 %0, %1, %2" : "=v"(r) : "v"(lo), "v"(hi));
  return r;
}

static __device__ __forceinline__ f32x16 mfma_bf16(bf16x8 a, bf16x8 b, f32x16 c) {
  return __builtin_amdgcn_mfma_f32_32x32x16_bf16(a, b, c, 0, 0, 0);
}

static __device__ __forceinline__ float nt_load(const float* p) {
  return __builtin_nontemporal_load(p);   // read + evict hint (dead-after-read only)
}

// LDS-only barrier: drains lgkmcnt, leaves vmcnt in flight (proven safe R14;
// only inter-wave dependency is lgt[] in LDS).
static __device__ __forceinline__ void lds_barrier() {
  asm volatile("s_waitcnt lgkmcnt(0)\n\ts_barrier" ::: "memory");
}

// A operand for U^T = W^T(d x p) @ X^T(p x b), one (i,j), from raw f32 W.
// lane l: m = d = l&31, k = p = 8*(l>>5) + e  (e = 0..7)
static __device__ __forceinline__ bf16x8 load_wfrag_f32(const float* __restrict__ W,
                                                        int i, int j, int h, int d) {
  const float* wp = W + (((size_t)i * NJ + j) * NP + h * 8) * ND + d;
  union { unsigned u[4]; bf16x8 v; } wf;
  wf.u[0] = cvt_pk_bf16(wp[0 * ND], wp[1 * ND]);
  wf.u[1] = cvt_pk_bf16(wp[2 * ND], wp[3 * ND]);
  wf.u[2] = cvt_pk_bf16(wp[4 * ND], wp[5 * ND]);
  wf.u[3] = cvt_pk_bf16(wp[6 * ND], wp[7 * ND]);
  return wf.v;
}

// B operand: lane l: k = p = 8*(l>>5)+e, n = b = l&31
static __device__ __forceinline__ bf16x8 load_xfrag(const unsigned short* __restrict__ Xt,
                                                    int i, int b, int h) {
  return *(const bf16x8*)(Xt + ((size_t)i * NB + b) * NP + h * 8);
}

// ---------- prep: inputs[b][i][p] (f32) -> Xt[i][b][p] (bf16) ----------
__global__ __launch_bounds__(256) void kern_prep(const float* __restrict__ in,
                                                 unsigned short* __restrict__ Xt) {
  const int t = blockIdx.x * 256 + threadIdx.x;   // 262144 threads, 4 elems each
  const int rest = t >> 2;                        // b*NI + i
  const int p4 = (t & 3) * 4;
  const int i = rest & (NI - 1);
  const int b = rest >> 11;
  f32x4 x = *(const f32x4*)(in + (size_t)rest * NP + p4);
  uint2 v;
  v.x = cvt_pk_bf16(x[0], x[1]);
  v.y = cvt_pk_bf16(x[2], x[3]);
  *(uint2*)(Xt + ((size_t)i * NB + b) * NP + p4) = v;
}

// ---------- fused routing pass over an i-chunk ----------
// 512 threads = 8 waves; wave w owns j = w*4 + t (t=0..3); block ch covers ipb i's.
// R15: TLP fix — grid nch=512 (ipb=4) => 2 blocks/CU co-resident = 4 waves/EU
// (was 2/EU; R11 showed VALUBusy 1.7% = latency-starved; ILP fixes R13/R14
// were neutral). Register diet to protect 2-block residency: eager W->bf16
// (no raw-f32 pipeline regs); ~116 total regs/wave incl 64 AGPR (sacc).
// sacc stays pure-MFMA C/D; softmax c applied via re-MFMA with c-scaled B.
template <bool UNIFORM>
__global__ __attribute__((amdgpu_waves_per_eu(2, 2)))
__launch_bounds__(512) void kern_fused(const float* __restrict__ W,
                                       const unsigned short* __restrict__ Xt,
                                       const float* __restrict__ vsum,
                                       float* __restrict__ part,
                                       int ipb, int nch) {
  const int tid = threadIdx.x;
  const int w = tid >> 6;
  const int lane = tid & 63;
  const int b = lane & 31;
  const int h = lane >> 5;
  const int ch = blockIdx.x;
  const int i0 = ch * ipb;

  // register-resident vsum fragment: vs[t][q][e] = vsum[b][j=w*4+t][8q + 4h + e]
  f32x4 vs[4][4];
  if (!UNIFORM) {
#pragma unroll
    for (int t = 0; t < 4; ++t) {
      const int j = w * 4 + t;
#pragma unroll
      for (int q = 0; q < 4; ++q)
        vs[t][q] = *(const f32x4*)(vsum + ((size_t)b * NJ + j) * ND + q * 8 + h * 4);
    }
  }

  f32x16 sacc[4] = {};
  __shared__ float lgt[NJ][33];

  for (int ii = 0; ii < ipb; ++ii) {
    const int i = i0 + ii;
    const bf16x8 xf = load_xfrag(Xt, i, b, h);
    if (UNIFORM) {
#pragma unroll
      for (int t = 0; t < 4; ++t)
        sacc[t] = mfma_bf16(load_wfrag_f32(W, i, w * 4 + t, h, b), xf, sacc[t]);
    } else {
      // unpack this lane's 8 bf16 x-values to f32 (for the c-scaled re-pack)
      union { bf16x8 v; unsigned short s[8]; } xu; xu.v = xf;
      float xf32[8];
#pragma unroll
      for (int e = 0; e < 8; ++e)
        xf32[e] = __uint_as_float((unsigned)xu.s[e] << 16);

      bf16x8 wf[4];
      float lg[4];
#pragma unroll
      for (int t = 0; t < 4; ++t) {
        wf[t] = load_wfrag_f32(W, i, w * 4 + t, h, b);
        f32x16 z = {};
        const f32x16 um = mfma_bf16(wf[t], xf, z);   // transient: dies before barrier
        float p = 0.f;
#pragma unroll
        for (int r = 0; r < 16; ++r)
          p += um[r] * vs[t][r >> 2][r & 3];         // d(r) = (r&3) + 8*(r>>2) + 4h
        p += __shfl_xor(p, 32);                      // add partner half's 16 d's
        lg[t] = p;
      }
      if (h == 0) {
#pragma unroll
        for (int t = 0; t < 4; ++t) lgt[w * 4 + t][b] = lg[t];
      }
      lds_barrier();                                 // lgkmcnt-only (R14, proven)
      // per-(b,i) softmax over j (each thread reduces its own b's column)
      float mx = -3.0e38f;
#pragma unroll
      for (int jj = 0; jj < NJ; ++jj) mx = fmaxf(mx, lgt[jj][b]);
      float den = 0.f;
#pragma unroll
      for (int jj = 0; jj < NJ; ++jj) den += expf(lgt[jj][b] - mx);
      const float inv = 1.0f / den;
#pragma unroll
      for (int t = 0; t < 4; ++t) {
        const float c = expf(lg[t] - mx) * inv;
        union { unsigned u[4]; bf16x8 v; } xc;
#pragma unroll
        for (int e = 0; e < 4; ++e)
          xc.u[e] = cvt_pk_bf16(xf32[2 * e] * c, xf32[2 * e + 1] * c);
        sacc[t] = mfma_bf16(wf[t], xc.v, sacc[t]);   // sacc stays pure-MFMA
      }
      lds_barrier();   // protect lgt before next i overwrites it
    }
  }

  // epilogue: 4 contiguous f32x4 stores per (t).
#pragma unroll
  for (int t = 0; t < 4; ++t) {
    const int j = w * 4 + t;
    float* base = &part[(((size_t)j * nch + ch) * NB + b) * ND];
#pragma unroll
    for (int rq = 0; rq < 4; ++rq) {
      f32x4 v4;
#pragma unroll
      for (int e = 0; e < 4; ++e) {
        const float val = UNIFORM ? sacc[t][rq * 4 + e] * (1.0f / 32.0f)
                                  : sacc[t][rq * 4 + e];
        v4[e] = val;
      }
      *(f32x4*)(base + rq * 8 + 4 * h) = v4;   // d = 8*rq + 4h + e
    }
  }
}

// ---------- stage-1 reduce: 32-chunk groups -> part2[j][r][b][d] ----------
// nt_load: part is dead after this read -> evict-hint frees L2/L3 for W.
__global__ __launch_bounds__(1024) void kern_reduce1(const float* __restrict__ part,
                                                     float* __restrict__ part2,
                                                     int nch, int RG) {
  const int j = blockIdx.x / RG;
  const int r = blockIdx.x % RG;
  const int t = threadIdx.x;
  const int b = t >> 5;
  const int d = t & 31;
  float s = 0.f;
#pragma unroll 4
  for (int c = 0; c < 32; ++c)
    s += nt_load(&part[(((size_t)j * nch + r * 32 + c) * NB + b) * ND + d]);
  part2[(((size_t)j * RG + r) * NB + b) * ND + d] = s;
}

// ---------- final reduce + squash + vsum/out ----------
__global__ __launch_bounds__(1024) void kern_squash(const float* __restrict__ part2,
                                                    float* __restrict__ vsum,
                                                    float* __restrict__ out,
                                                    int mode, int RG) {
  const int j = blockIdx.x;
  const int t = threadIdx.x;
  const int b = t >> 5;
  const int d = t & 31;
  float s = 0.f;
  for (int r = 0; r < RG; ++r)
    s += nt_load(&part2[(((size_t)j * RG + r) * NB + b) * ND + d]);

  __shared__ float sl[32][33];
  __shared__ float fb[32];
  sl[b][d] = s;
  __syncthreads();
  if (t < 32) {
    float n2 = 0.f;
#pragma unroll
    for (int dd = 0; dd < ND; ++dd) { const float x = sl[t][dd]; n2 += x * x; }
    fb[t] = n2 / ((1.0f + n2) * sqrtf(n2 + EPSF));
  }
  __syncthreads();
  const float v = s * fb[b];
  const int idx = (b * NJ + j) * ND + d;
  if (mode == 0)      vsum[idx] = v;        // iter0: vsum := v0 (never read-before-write)
  else if (mode == 1) vsum[idx] += v;       // iter1: vsum := v0+v1
  else                out[idx] = v;         // iter2: final output [B,J,D]
}

extern "C" void kernel_launch(void* const* d_in, const int* in_sizes, int n_in,
                              void* d_out, int out_size, void* d_ws, size_t ws_size,
                              hipStream_t stream) {
  const float* inp = (const float*)d_in[0];
  const float* W   = (const float*)d_in[1];
  // defensive: inputs is 1M elems, W is 33.5M elems
  if (n_in >= 2 && in_sizes[0] > in_sizes[1]) { const float* tmp = inp; inp = W; W = tmp; }
  float* out = (float*)d_out;
  char* ws = (char*)d_ws;
  (void)out_size;

  // layout: Xt@0 (2MB) | part (nch*128KB) | vsum (128KB) | part2 (RG*128KB)
  // nch=512 -> 2 blocks/CU (TLP). Adaptive fallback preserved.
  int nch = 512;
  while (nch > 32 &&
         (size_t)(2u << 20) + (size_t)nch * 131072u + 131072u +
             (size_t)(nch / 32) * 131072u > ws_size)
    nch >>= 1;
  const int ipb = NI / nch;
  const int RG = nch / 32;

  unsigned short* Xt = (unsigned short*)ws;
  float* part  = (float*)(ws + (2u << 20));
  float* vsum  = part + (size_t)NJ * nch * NB * ND;   // full part extent
  float* part2 = vsum + (size_t)NB * NJ * ND;         // after vsum

  kern_prep<<<1024, 256, 0, stream>>>(inp, Xt);

  // iter 0: uniform c = 1/32
  kern_fused<true><<<nch, 512, 0, stream>>>(W, Xt, nullptr, part, ipb, nch);
  kern_reduce1<<<32 * RG, 1024, 0, stream>>>(part, part2, nch, RG);
  kern_squash<<<32, 1024, 0, stream>>>(part2, vsum, out, 0, RG);

  // iter 1
  kern_fused<false><<<nch, 512, 0, stream>>>(W, Xt, vsum, part, ipb, nch);
  kern_reduce1<<<32 * RG, 1024, 0, stream>>>(part, part2, nch, RG);
  kern_squash<<<32, 1024, 0, stream>>>(part2, vsum, out, 1, RG);

  // iter 2
  kern_fused<false><<<nch, 512, 0, stream>>>(W, Xt, vsum, part, ipb, nch);
  kern_reduce1<<<32 * RG, 1024, 0, stream>>>(part, part2, nch, RG);
  kern_squash<<<32, 1024, 0, stream>>>(part2, vsum, out, 2, RG);
}

// Round 16
// 175.402 us; speedup vs baseline: 1.2178x; 1.2178x over previous
//
#include <hip/hip_runtime.h>

#define NB 32
#define NI 2048
#define NP 16
#define NJ 32
#define ND 32
#define EPSF 1e-7f

typedef __attribute__((ext_vector_type(8))) short bf16x8;
typedef __attribute__((ext_vector_type(16))) float f32x16;
typedef __attribute__((ext_vector_type(4))) float f32x4;

static __device__ __forceinline__ unsigned cvt_pk_bf16(float lo, float hi) {
  unsigned r;
  asm("v_cvt_pk_bf16_f32 %0, %1, %2" : "=v"(r) : "v"(lo), "v"(hi));
  return r;
}

static __device__ __forceinline__ f32x16 mfma_bf16(bf16x8 a, bf16x8 b, f32x16 c) {
  return __builtin_amdgcn_mfma_f32_32x32x16_bf16(a, b, c, 0, 0, 0);
}

static __device__ __forceinline__ float nt_load(const float* p) {
  return __builtin_nontemporal_load(p);   // read + evict hint (dead-after-read only)
}

// LDS-only barrier: drains lgkmcnt, leaves vmcnt in flight (proven safe R14).
static __device__ __forceinline__ void lds_barrier() {
  asm volatile("s_waitcnt lgkmcnt(0)\n\ts_barrier" ::: "memory");
}

// Raw W row gather for one (i,j): 8 f32 at stride ND; convert at use.
struct wraw { float f[8]; };
static __device__ __forceinline__ wraw load_wraw(const float* __restrict__ W,
                                                 int i, int j, int h, int d) {
  const float* wp = W + (((size_t)i * NJ + j) * NP + h * 8) * ND + d;
  wraw r;
#pragma unroll
  for (int e = 0; e < 8; ++e) r.f[e] = wp[e * ND];
  return r;
}
// A operand: lane l: m = d = l&31, k = p = 8*(l>>5) + e
static __device__ __forceinline__ bf16x8 pack_wfrag(const wraw& r) {
  union { unsigned u[4]; bf16x8 v; } wf;
  wf.u[0] = cvt_pk_bf16(r.f[0], r.f[1]);
  wf.u[1] = cvt_pk_bf16(r.f[2], r.f[3]);
  wf.u[2] = cvt_pk_bf16(r.f[4], r.f[5]);
  wf.u[3] = cvt_pk_bf16(r.f[6], r.f[7]);
  return wf.v;
}

// B operand: lane l: k = p = 8*(l>>5)+e, n = b = l&31
static __device__ __forceinline__ bf16x8 load_xfrag(const unsigned short* __restrict__ Xt,
                                                    int i, int b, int h) {
  return *(const bf16x8*)(Xt + ((size_t)i * NB + b) * NP + h * 8);
}

// ---------- prep: inputs[b][i][p] (f32) -> Xt[i][b][p] (bf16) ----------
__global__ __launch_bounds__(256) void kern_prep(const float* __restrict__ in,
                                                 unsigned short* __restrict__ Xt) {
  const int t = blockIdx.x * 256 + threadIdx.x;   // 262144 threads, 4 elems each
  const int rest = t >> 2;                        // b*NI + i
  const int p4 = (t & 3) * 4;
  const int i = rest & (NI - 1);
  const int b = rest >> 11;
  f32x4 x = *(const f32x4*)(in + (size_t)rest * NP + p4);
  uint2 v;
  v.x = cvt_pk_bf16(x[0], x[1]);
  v.y = cvt_pk_bf16(x[2], x[3]);
  *(uint2*)(Xt + ((size_t)i * NB + b) * NP + p4) = v;
}

// ---------- fused routing pass over an i-chunk ----------
// 512 threads = 8 waves; wave w owns j = w*4 + t (t=0..3); block ch covers ipb i's.
// R16: 2 i's PER LOOP ITERATION — both i's loads issued up front (2x MLP),
// ONE barrier pair for both (barriers/i halved), lgt relaid as [b][j] so the
// softmax LDS phase is 1x f32x4 write + 8x f32x4 reads (was 4+32 scalars,
// serial fmax-on-LDS chain). Arithmetic bit-identical to R13 (same per-i ops,
// a-then-b accumulation order). sacc pure-MFMA (AGPR); c via re-MFMA of
// c-scaled B. nch=256 (R15's 512 doubled part traffic: regression).
template <bool UNIFORM>
__global__ __attribute__((amdgpu_waves_per_eu(2, 2)))
__launch_bounds__(512) void kern_fused(const float* __restrict__ W,
                                       const unsigned short* __restrict__ Xt,
                                       const float* __restrict__ vsum,
                                       float* __restrict__ part,
                                       int ipb, int nch) {
  const int tid = threadIdx.x;
  const int w = tid >> 6;
  const int lane = tid & 63;
  const int b = lane & 31;
  const int h = lane >> 5;
  const int ch = blockIdx.x;
  const int i0 = ch * ipb;

  // register-resident vsum fragment: vs[t][q][e] = vsum[b][j=w*4+t][8q + 4h + e]
  f32x4 vs[4][4];
  if (!UNIFORM) {
#pragma unroll
    for (int t = 0; t < 4; ++t) {
      const int j = w * 4 + t;
#pragma unroll
      for (int q = 0; q < 4; ++q)
        vs[t][q] = *(const f32x4*)(vsum + ((size_t)b * NJ + j) * ND + q * 8 + h * 4);
    }
  }

  f32x16 sacc[4] = {};
  __shared__ float lgtA[NB][33];   // [b][j]: f32x4-vectorized write/read, conflict-free
  __shared__ float lgtB[NB][33];

  for (int it = 0; it < ipb / 2; ++it) {
    const int ia = i0 + 2 * it;
    const int ib = ia + 1;

    // ---- issue ALL loads for both i's up front (max in-flight) ----
    wraw wra[4], wrb[4];
#pragma unroll
    for (int t = 0; t < 4; ++t) wra[t] = load_wraw(W, ia, w * 4 + t, h, b);
#pragma unroll
    for (int t = 0; t < 4; ++t) wrb[t] = load_wraw(W, ib, w * 4 + t, h, b);
    const bf16x8 xfa = load_xfrag(Xt, ia, b, h);
    const bf16x8 xfb = load_xfrag(Xt, ib, b, h);

    bf16x8 wfa[4], wfb[4];
#pragma unroll
    for (int t = 0; t < 4; ++t) wfa[t] = pack_wfrag(wra[t]);
#pragma unroll
    for (int t = 0; t < 4; ++t) wfb[t] = pack_wfrag(wrb[t]);

    if (UNIFORM) {
#pragma unroll
      for (int t = 0; t < 4; ++t) {
        sacc[t] = mfma_bf16(wfa[t], xfa, sacc[t]);
        sacc[t] = mfma_bf16(wfb[t], xfb, sacc[t]);
      }
    } else {
      // unpack both lanes' x to f32 (for the c-scaled re-pack)
      union { bf16x8 v; unsigned short s[8]; } xua, xub;
      xua.v = xfa; xub.v = xfb;
      float xfa32[8], xfb32[8];
#pragma unroll
      for (int e = 0; e < 8; ++e) {
        xfa32[e] = __uint_as_float((unsigned)xua.s[e] << 16);
        xfb32[e] = __uint_as_float((unsigned)xub.s[e] << 16);
      }

      union { float f[4]; f32x4 v; } lga, lgb;
#pragma unroll
      for (int t = 0; t < 4; ++t) {
        f32x16 z = {};
        const f32x16 um = mfma_bf16(wfa[t], xfa, z);
        float p = 0.f;
#pragma unroll
        for (int r = 0; r < 16; ++r)
          p += um[r] * vs[t][r >> 2][r & 3];   // d(r) = (r&3) + 8*(r>>2) + 4h
        p += __shfl_xor(p, 32);
        lga.f[t] = p;
      }
#pragma unroll
      for (int t = 0; t < 4; ++t) {
        f32x16 z = {};
        const f32x16 um = mfma_bf16(wfb[t], xfb, z);
        float p = 0.f;
#pragma unroll
        for (int r = 0; r < 16; ++r)
          p += um[r] * vs[t][r >> 2][r & 3];
        p += __shfl_xor(p, 32);
        lgb.f[t] = p;
      }
      if (h == 0) {
        *(f32x4*)&lgtA[b][w * 4] = lga.v;     // one ds_write_b128 each
        *(f32x4*)&lgtB[b][w * 4] = lgb.v;
      }
      lds_barrier();

      // softmax over j for this lane's b: 8x f32x4 reads, conflict-free
      float mxa = -3.0e38f, mxb = -3.0e38f;
      float va[8][4], vb[8][4];
#pragma unroll
      for (int q = 0; q < 8; ++q) {
        const f32x4 ra = *(const f32x4*)&lgtA[b][q * 4];
        const f32x4 rb = *(const f32x4*)&lgtB[b][q * 4];
#pragma unroll
        for (int e = 0; e < 4; ++e) {
          va[q][e] = ra[e]; vb[q][e] = rb[e];
          mxa = fmaxf(mxa, ra[e]); mxb = fmaxf(mxb, rb[e]);
        }
      }
      float dena = 0.f, denb = 0.f;
#pragma unroll
      for (int q = 0; q < 8; ++q)
#pragma unroll
        for (int e = 0; e < 4; ++e) {
          dena += expf(va[q][e] - mxa);
          denb += expf(vb[q][e] - mxb);
        }
      const float inva = 1.0f / dena, invb = 1.0f / denb;
#pragma unroll
      for (int t = 0; t < 4; ++t) {
        const float ca = expf(lga.f[t] - mxa) * inva;
        union { unsigned u[4]; bf16x8 v; } xc;
#pragma unroll
        for (int e = 0; e < 4; ++e)
          xc.u[e] = cvt_pk_bf16(xfa32[2 * e] * ca, xfa32[2 * e + 1] * ca);
        sacc[t] = mfma_bf16(wfa[t], xc.v, sacc[t]);
      }
#pragma unroll
      for (int t = 0; t < 4; ++t) {
        const float cb = expf(lgb.f[t] - mxb) * invb;
        union { unsigned u[4]; bf16x8 v; } xc;
#pragma unroll
        for (int e = 0; e < 4; ++e)
          xc.u[e] = cvt_pk_bf16(xfb32[2 * e] * cb, xfb32[2 * e + 1] * cb);
        sacc[t] = mfma_bf16(wfb[t], xc.v, sacc[t]);
      }
      lds_barrier();   // protect lgt before next pair overwrites it
    }
  }

  // epilogue: 4 contiguous f32x4 stores per (t).
#pragma unroll
  for (int t = 0; t < 4; ++t) {
    const int j = w * 4 + t;
    float* base = &part[(((size_t)j * nch + ch) * NB + b) * ND];
#pragma unroll
    for (int rq = 0; rq < 4; ++rq) {
      f32x4 v4;
#pragma unroll
      for (int e = 0; e < 4; ++e) {
        const float val = UNIFORM ? sacc[t][rq * 4 + e] * (1.0f / 32.0f)
                                  : sacc[t][rq * 4 + e];
        v4[e] = val;
      }
      *(f32x4*)(base + rq * 8 + 4 * h) = v4;   // d = 8*rq + 4h + e
    }
  }
}

// ---------- stage-1 reduce: 32-chunk groups -> part2[j][r][b][d] ----------
__global__ __launch_bounds__(1024) void kern_reduce1(const float* __restrict__ part,
                                                     float* __restrict__ part2,
                                                     int nch, int RG) {
  const int j = blockIdx.x / RG;
  const int r = blockIdx.x % RG;
  const int t = threadIdx.x;
  const int b = t >> 5;
  const int d = t & 31;
  float s = 0.f;
#pragma unroll 4
  for (int c = 0; c < 32; ++c)
    s += nt_load(&part[(((size_t)j * nch + r * 32 + c) * NB + b) * ND + d]);
  part2[(((size_t)j * RG + r) * NB + b) * ND + d] = s;
}

// ---------- final reduce + squash + vsum/out ----------
__global__ __launch_bounds__(1024) void kern_squash(const float* __restrict__ part2,
                                                    float* __restrict__ vsum,
                                                    float* __restrict__ out,
                                                    int mode, int RG) {
  const int j = blockIdx.x;
  const int t = threadIdx.x;
  const int b = t >> 5;
  const int d = t & 31;
  float s = 0.f;
  for (int r = 0; r < RG; ++r)
    s += nt_load(&part2[(((size_t)j * RG + r) * NB + b) * ND + d]);

  __shared__ float sl[32][33];
  __shared__ float fb[32];
  sl[b][d] = s;
  __syncthreads();
  if (t < 32) {
    float n2 = 0.f;
#pragma unroll
    for (int dd = 0; dd < ND; ++dd) { const float x = sl[t][dd]; n2 += x * x; }
    fb[t] = n2 / ((1.0f + n2) * sqrtf(n2 + EPSF));
  }
  __syncthreads();
  const float v = s * fb[b];
  const int idx = (b * NJ + j) * ND + d;
  if (mode == 0)      vsum[idx] = v;        // iter0: vsum := v0 (never read-before-write)
  else if (mode == 1) vsum[idx] += v;       // iter1: vsum := v0+v1
  else                out[idx] = v;         // iter2: final output [B,J,D]
}

extern "C" void kernel_launch(void* const* d_in, const int* in_sizes, int n_in,
                              void* d_out, int out_size, void* d_ws, size_t ws_size,
                              hipStream_t stream) {
  const float* inp = (const float*)d_in[0];
  const float* W   = (const float*)d_in[1];
  // defensive: inputs is 1M elems, W is 33.5M elems
  if (n_in >= 2 && in_sizes[0] > in_sizes[1]) { const float* tmp = inp; inp = W; W = tmp; }
  float* out = (float*)d_out;
  char* ws = (char*)d_ws;
  (void)out_size;

  // proven layout: Xt@0 (2MB) | part (nch*128KB) | vsum (128KB) | part2 (RG*128KB)
  int nch = 256;
  while (nch > 32 &&
         (size_t)(2u << 20) + (size_t)nch * 131072u + 131072u +
             (size_t)(nch / 32) * 131072u > ws_size)
    nch >>= 1;
  const int ipb = NI / nch;
  const int RG = nch / 32;

  unsigned short* Xt = (unsigned short*)ws;
  float* part  = (float*)(ws + (2u << 20));
  float* vsum  = part + (size_t)NJ * nch * NB * ND;   // full part extent
  float* part2 = vsum + (size_t)NB * NJ * ND;         // after vsum

  kern_prep<<<1024, 256, 0, stream>>>(inp, Xt);

  // iter 0: uniform c = 1/32
  kern_fused<true><<<nch, 512, 0, stream>>>(W, Xt, nullptr, part, ipb, nch);
  kern_reduce1<<<32 * RG, 1024, 0, stream>>>(part, part2, nch, RG);
  kern_squash<<<32, 1024, 0, stream>>>(part2, vsum, out, 0, RG);

  // iter 1
  kern_fused<false><<<nch, 512, 0, stream>>>(W, Xt, vsum, part, ipb, nch);
  kern_reduce1<<<32 * RG, 1024, 0, stream>>>(part, part2, nch, RG);
  kern_squash<<<32, 1024, 0, stream>>>(part2, vsum, out, 1, RG);

  // iter 2
  kern_fused<false><<<nch, 512, 0, stream>>>(W, Xt, vsum, part, ipb, nch);
  kern_reduce1<<<32 * RG, 1024, 0, stream>>>(part, part2, nch, RG);
  kern_squash<<<32, 1024, 0, stream>>>(part2, vsum, out, 2, RG);
}

// Round 19
// 162.892 us; speedup vs baseline: 1.3113x; 1.0768x over previous
//
#include <hip/hip_runtime.h>

#define NB 32
#define NI 2048
#define NP 16
#define NJ 32
#define ND 32
#define EPSF 1e-7f

typedef __attribute__((ext_vector_type(8))) short bf16x8;
typedef __attribute__((ext_vector_type(16))) float f32x16;
typedef __attribute__((ext_vector_type(4))) float f32x4;

static __device__ __forceinline__ unsigned cvt_pk_bf16(float lo, float hi) {
  unsigned r;
  asm("v_cvt_pk_bf16_f32 %0, %1, %2" : "=v"(r) : "v"(lo), "v"(hi));
  return r;
}

static __device__ __forceinline__ f32x16 mfma_bf16(bf16x8 a, bf16x8 b, f32x16 c) {
  return __builtin_amdgcn_mfma_f32_32x32x16_bf16(a, b, c, 0, 0, 0);
}

static __device__ __forceinline__ float nt_load(const float* p) {
  return __builtin_nontemporal_load(p);   // dead-after-read streams only
}

// lgkm-only barrier for the lgt softmax exchange (R14-proven): drains LDS ops,
// leaves prefetched global loads (vmcnt) in flight.
static __device__ __forceinline__ void lds_barrier() {
  asm volatile("s_waitcnt lgkmcnt(0)\n\ts_barrier" ::: "memory");
}

// B operand: lane l: k = p = 8*(l>>5)+e, n = b = l&31
static __device__ __forceinline__ bf16x8 load_xfrag(const unsigned short* __restrict__ Xt,
                                                    int i, int b, int h) {
  return *(const bf16x8*)(Xt + ((size_t)i * NB + b) * NP + h * 8);
}

// ---------- prep: inputs[b][i][p] (f32) -> Xt[i][b][p] (bf16) ----------
__global__ __launch_bounds__(256) void kern_prep(const float* __restrict__ in,
                                                 unsigned short* __restrict__ Xt) {
  const int t = blockIdx.x * 256 + threadIdx.x;
  const int rest = t >> 2;
  const int p4 = (t & 3) * 4;
  const int i = rest & (NI - 1);
  const int b = rest >> 11;
  f32x4 x = *(const f32x4*)(in + (size_t)rest * NP + p4);
  uint2 v;
  v.x = cvt_pk_bf16(x[0], x[1]);
  v.y = cvt_pk_bf16(x[2], x[3]);
  *(uint2*)(Xt + ((size_t)i * NB + b) * NP + p4) = v;
}

// ---------- fused routing pass over an i-chunk (wave-private reg-staged W) ----
// 512 threads = 8 waves; wave w owns j = w*4+t (t=0..3); block ch covers ipb i's.
// R19: W loaded as CONTIGUOUS lane-major dwordx4 streams (lane l holds
// W[i][j][p=l>>2][d=(l&3)*8+0..7]), cvt'd to bf16, ds_write_b128 into a
// WAVE-PRIVATE 4KB LDS slice, frag-read back (8x ds_read_u16, <=2-way banks).
// No cross-wave W sync needed (each wave reads only its own slice); the only
// barriers are lgt's lgkm-only pair. Next-i loads prefetched into regs and
// survive those barriers. cvt on same floats => frags bit-identical to R13
// (absmax canary 0.00390625). <=64KB static LDS: no dynamic-smem attribute
// (R18's 136KB request = suspected launch failure).
template <bool UNIFORM>
__global__ __attribute__((amdgpu_waves_per_eu(2, 2)))
__launch_bounds__(512) void kern_fused(const float* __restrict__ W,
                                       const unsigned short* __restrict__ Xt,
                                       const float* __restrict__ vsum,
                                       float* __restrict__ part,
                                       int ipb, int nch) {
  const int tid = threadIdx.x;
  const int w = tid >> 6;
  const int lane = tid & 63;
  const int b = lane & 31;
  const int h = lane >> 5;
  const int ch = blockIdx.x;
  const int i0 = ch * ipb;

  __shared__ uint4 Wbf4[8][4][64];          // 32 KB: [wave][t][lane] = 8 bf16
  __shared__ float lgt[NJ][33];             // 4.2 KB

  // vsum fragment: vs[t][q][e] = vsum[b][j=w*4+t][8q + 4h + e]
  f32x4 vs[4][4];
  if (!UNIFORM) {
#pragma unroll
    for (int t = 0; t < 4; ++t) {
      const int j = w * 4 + t;
#pragma unroll
      for (int q = 0; q < 4; ++q)
        vs[t][q] = *(const f32x4*)(vsum + ((size_t)b * NJ + j) * ND + q * 8 + h * 4);
    }
  }

  f32x16 sacc[4] = {};

  // prefetch W(i0): per t, lane l loads floats [l*8, l*8+8) of the 2KB block
  f32x4 wnA[4], wnB[4];
#pragma unroll
  for (int t = 0; t < 4; ++t) {
    const float* g = W + ((size_t)(i0 * NJ + w * 4 + t)) * (NP * ND) + lane * 8;
    wnA[t] = *(const f32x4*)g;
    wnB[t] = *(const f32x4*)(g + 4);
  }

  const unsigned short* wslab = (const unsigned short*)&Wbf4[w][0][0];

  for (int ii = 0; ii < ipb; ++ii) {
    const int i = i0 + ii;

    // ---- stage current W into wave-private LDS slice (bf16) ----
#pragma unroll
    for (int t = 0; t < 4; ++t) {
      uint4 pk;
      pk.x = cvt_pk_bf16(wnA[t][0], wnA[t][1]);
      pk.y = cvt_pk_bf16(wnA[t][2], wnA[t][3]);
      pk.z = cvt_pk_bf16(wnB[t][0], wnB[t][1]);
      pk.w = cvt_pk_bf16(wnB[t][2], wnB[t][3]);
      Wbf4[w][t][lane] = pk;     // ushort idx (l>>2)*32+(l&3)*8 = p*32+d
    }

    // ---- prefetch next i's W (stays in flight across the lgt barriers) ----
    if (ii + 1 < ipb) {
#pragma unroll
      for (int t = 0; t < 4; ++t) {
        const float* g = W + ((size_t)((i + 1) * NJ + w * 4 + t)) * (NP * ND) + lane * 8;
        wnA[t] = *(const f32x4*)g;
        wnB[t] = *(const f32x4*)(g + 4);
      }
    }
    const bf16x8 xf = load_xfrag(Xt, i, b, h);

    // same-wave DS in-order + TBAA guard: writes visible before frag reads
    asm volatile("s_waitcnt lgkmcnt(0)" ::: "memory");

    // ---- frag read: lane (b,h) gathers W[p=8h+e][d=b], e=0..7 ----
    bf16x8 wf[4];
#pragma unroll
    for (int t = 0; t < 4; ++t) {
      union { unsigned short s[8]; bf16x8 v; } uf;
#pragma unroll
      for (int e = 0; e < 8; ++e)
        uf.s[e] = wslab[t * 512 + (h * 8 + e) * 32 + b];
      wf[t] = uf.v;
    }

    if (UNIFORM) {
#pragma unroll
      for (int t = 0; t < 4; ++t) sacc[t] = mfma_bf16(wf[t], xf, sacc[t]);
    } else {
      union { bf16x8 v; unsigned short s[8]; } xu; xu.v = xf;
      float xf32[8];
#pragma unroll
      for (int e = 0; e < 8; ++e)
        xf32[e] = __uint_as_float((unsigned)xu.s[e] << 16);

      float lg[4];
#pragma unroll
      for (int t = 0; t < 4; ++t) {
        f32x16 z = {};
        const f32x16 um = mfma_bf16(wf[t], xf, z);   // transient
        float p = 0.f;
#pragma unroll
        for (int r = 0; r < 16; ++r)
          p += um[r] * vs[t][r >> 2][r & 3];         // d(r) = (r&3)+8*(r>>2)+4h
        p += __shfl_xor(p, 32);
        lg[t] = p;
      }
      if (h == 0) {
#pragma unroll
        for (int t = 0; t < 4; ++t) lgt[w * 4 + t][b] = lg[t];
      }
      lds_barrier();
      float mx = -3.0e38f;
#pragma unroll
      for (int jj = 0; jj < NJ; ++jj) mx = fmaxf(mx, lgt[jj][b]);
      float den = 0.f;
#pragma unroll
      for (int jj = 0; jj < NJ; ++jj) den += expf(lgt[jj][b] - mx);
      const float inv = 1.0f / den;
#pragma unroll
      for (int t = 0; t < 4; ++t) {
        const float c = expf(lg[t] - mx) * inv;
        union { unsigned u[4]; bf16x8 v; } xc;
#pragma unroll
        for (int e = 0; e < 4; ++e)
          xc.u[e] = cvt_pk_bf16(xf32[2 * e] * c, xf32[2 * e + 1] * c);
        sacc[t] = mfma_bf16(wf[t], xc.v, sacc[t]);   // sacc pure-MFMA (AGPR)
      }
      lds_barrier();   // protect lgt before next i overwrites it
    }
  }

  // epilogue: 4 contiguous f32x4 stores per (t)
#pragma unroll
  for (int t = 0; t < 4; ++t) {
    const int j = w * 4 + t;
    float* base = &part[(((size_t)j * nch + ch) * NB + b) * ND];
#pragma unroll
    for (int rq = 0; rq < 4; ++rq) {
      f32x4 v4;
#pragma unroll
      for (int e = 0; e < 4; ++e) {
        const float val = UNIFORM ? sacc[t][rq * 4 + e] * (1.0f / 32.0f)
                                  : sacc[t][rq * 4 + e];
        v4[e] = val;
      }
      *(f32x4*)(base + rq * 8 + 4 * h) = v4;   // d = 8*rq + 4h + e
    }
  }
}

// ---------- stage-1 reduce: 32-chunk groups -> part2[j][r][b][d] ----------
__global__ __launch_bounds__(1024) void kern_reduce1(const float* __restrict__ part,
                                                     float* __restrict__ part2,
                                                     int nch, int RG) {
  const int j = blockIdx.x / RG;
  const int r = blockIdx.x % RG;
  const int t = threadIdx.x;
  const int b = t >> 5;
  const int d = t & 31;
  float s = 0.f;
#pragma unroll 4
  for (int c = 0; c < 32; ++c)
    s += nt_load(&part[(((size_t)j * nch + r * 32 + c) * NB + b) * ND + d]);
  part2[(((size_t)j * RG + r) * NB + b) * ND + d] = s;
}

// ---------- final reduce + squash + vsum/out ----------
__global__ __launch_bounds__(1024) void kern_squash(const float* __restrict__ part2,
                                                    float* __restrict__ vsum,
                                                    float* __restrict__ out,
                                                    int mode, int RG) {
  const int j = blockIdx.x;
  const int t = threadIdx.x;
  const int b = t >> 5;
  const int d = t & 31;
  float s = 0.f;
  for (int r = 0; r < RG; ++r)
    s += nt_load(&part2[(((size_t)j * RG + r) * NB + b) * ND + d]);

  __shared__ float sl[32][33];
  __shared__ float fb[32];
  sl[b][d] = s;
  __syncthreads();
  if (t < 32) {
    float n2 = 0.f;
#pragma unroll
    for (int dd = 0; dd < ND; ++dd) { const float x = sl[t][dd]; n2 += x * x; }
    fb[t] = n2 / ((1.0f + n2) * sqrtf(n2 + EPSF));
  }
  __syncthreads();
  const float v = s * fb[b];
  const int idx = (b * NJ + j) * ND + d;
  if (mode == 0)      vsum[idx] = v;        // iter0: vsum := v0
  else if (mode == 1) vsum[idx] += v;       // iter1: vsum := v0+v1
  else                out[idx] = v;         // iter2: final output [B,J,D]
}

extern "C" void kernel_launch(void* const* d_in, const int* in_sizes, int n_in,
                              void* d_out, int out_size, void* d_ws, size_t ws_size,
                              hipStream_t stream) {
  const float* inp = (const float*)d_in[0];
  const float* W   = (const float*)d_in[1];
  if (n_in >= 2 && in_sizes[0] > in_sizes[1]) { const float* tmp = inp; inp = W; W = tmp; }
  float* out = (float*)d_out;
  char* ws = (char*)d_ws;
  (void)out_size;

  // proven layout: Xt@0 (2MB) | part (nch*128KB) | vsum (128KB) | part2 (RG*128KB)
  int nch = 256;
  while (nch > 32 &&
         (size_t)(2u << 20) + (size_t)nch * 131072u + 131072u +
             (size_t)(nch / 32) * 131072u > ws_size)
    nch >>= 1;
  const int ipb = NI / nch;
  const int RG = nch / 32;

  unsigned short* Xt = (unsigned short*)ws;
  float* part  = (float*)(ws + (2u << 20));
  float* vsum  = part + (size_t)NJ * nch * NB * ND;
  float* part2 = vsum + (size_t)NB * NJ * ND;

  kern_prep<<<1024, 256, 0, stream>>>(inp, Xt);

  // iter 0: uniform c = 1/32
  kern_fused<true><<<nch, 512, 0, stream>>>(W, Xt, nullptr, part, ipb, nch);
  kern_reduce1<<<32 * RG, 1024, 0, stream>>>(part, part2, nch, RG);
  kern_squash<<<32, 1024, 0, stream>>>(part2, vsum, out, 0, RG);

  // iter 1
  kern_fused<false><<<nch, 512, 0, stream>>>(W, Xt, vsum, part, ipb, nch);
  kern_reduce1<<<32 * RG, 1024, 0, stream>>>(part, part2, nch, RG);
  kern_squash<<<32, 1024, 0, stream>>>(part2, vsum, out, 1, RG);

  // iter 2
  kern_fused<false><<<nch, 512, 0, stream>>>(W, Xt, vsum, part, ipb, nch);
  kern_reduce1<<<32 * RG, 1024, 0, stream>>>(part, part2, nch, RG);
  kern_squash<<<32, 1024, 0, stream>>>(part2, vsum, out, 2, RG);
}